// Round 3
// baseline (340.642 us; speedup 1.0000x reference)
//
#include <hip/hip_runtime.h>
#include <hip/hip_bf16.h>

namespace {

constexpr int N = 4096;
constexpr int D = 512;
constexpr int BM = 64;    // block tile (rows == cols)
constexpr int BK = 32;    // K-step per iteration
constexpr int KITERS = D / BK;  // 16
constexpr int NB = N / BM;      // 64 block-rows
constexpr int NBLK = NB * (NB + 1) / 2;  // 2080 upper-tri blocks

// workspace layout (bytes)
constexpr size_t OFF_XB  = 0;                          // bf16 X  [N*D]
constexpr size_t OFF_YB  = (size_t)N * D * 2;          // bf16 Y  [N*D]
constexpr size_t OFF_SQX = OFF_YB + (size_t)N * D * 2; // fp32 ||x_i||^2 [N]
constexpr size_t OFF_SQY = OFF_SQX + (size_t)N * 4;
constexpr size_t OFF_SX  = OFF_SQY + (size_t)N * 4;    // fp32 row sums KX [N]  (zeroed by prep)
constexpr size_t OFF_SY  = OFF_SX + (size_t)N * 4;     // fp32 row sums KY [N]  (zeroed by prep)
constexpr size_t OFF_T1  = OFF_SY + (size_t)N * 4;     // fp32 scalar sum(KX*KY)
constexpr size_t OFF_CNT = OFF_T1 + 4;                 // u32 completion counter
constexpr size_t WS_NEED = OFF_CNT + 4;

typedef __attribute__((ext_vector_type(8))) __bf16 bf16x8;
typedef __attribute__((ext_vector_type(4))) float floatx4;

__device__ inline void stage16(const void* g, void* l) {
  __builtin_amdgcn_global_load_lds(
      (const __attribute__((address_space(1))) unsigned int*)g,
      (__attribute__((address_space(3))) unsigned int*)l, 16, 0, 0);
}

__device__ inline unsigned short f2bf(float f) {
  __hip_bfloat16 h = __float2bfloat16(f);
  return __builtin_bit_cast(unsigned short, h);
}

// fp32 -> bf16 conversion + row squared norms. One wave per row (float4 loads,
// ushort4 stores), 4 rows per block, grid.y selects X vs Y.
// Also zeroes the accumulators (sX/sY/T1/counter) for this call.
__global__ void prep_kernel(const float* __restrict__ X, const float* __restrict__ Y,
                            unsigned short* __restrict__ Xb, unsigned short* __restrict__ Yb,
                            float* __restrict__ sqX, float* __restrict__ sqY,
                            float* __restrict__ sX, float* __restrict__ sY,
                            float* __restrict__ T1, unsigned int* __restrict__ cnt) {
  const int wave = threadIdx.x >> 6, lane = threadIdx.x & 63;
  const int row = blockIdx.x * 4 + wave;
  const int m = blockIdx.y;
  const float* __restrict__ src = m ? Y : X;
  unsigned short* __restrict__ dst = m ? Yb : Xb;
  float* __restrict__ dsq = m ? sqY : sqX;

  // zero accumulators: each (block,y) pair covers 4 entries
  if (threadIdx.x < 4) {
    float* z = m ? sY : sX;
    z[blockIdx.x * 4 + threadIdx.x] = 0.f;
  }
  if (blockIdx.x == 0 && m == 0 && threadIdx.x == 0) { *T1 = 0.f; *cnt = 0u; }

  const float4* s4 = (const float4*)(src + (size_t)row * D);
  ushort4* d4 = (ushort4*)(dst + (size_t)row * D);
  float acc = 0.f;
#pragma unroll
  for (int h = 0; h < 2; ++h) {
    float4 v = s4[lane + h * 64];
    acc += v.x * v.x + v.y * v.y + v.z * v.z + v.w * v.w;
    ushort4 o;
    o.x = f2bf(v.x); o.y = f2bf(v.y); o.z = f2bf(v.z); o.w = f2bf(v.w);
    d4[lane + h * 64] = o;
  }
#pragma unroll
  for (int mm = 32; mm >= 1; mm >>= 1) acc += __shfl_xor(acc, mm, 64);
  if (lane == 0) dsq[row] = acc;
}

// Upper-triangular fused Gram+RBF+reductions, 64x64 tiles, 4 waves each
// computing a 32x32 quadrant. Off-diag tiles: T1 weight 2, plus col sums
// feed rows J by symmetry. Last block to finish computes the final scalar.
__launch_bounds__(256, 4)
__global__ void hsic_main(const __hip_bfloat16* __restrict__ Xbh,
                          const __hip_bfloat16* __restrict__ Ybh,
                          const float* __restrict__ sqX, const float* __restrict__ sqY,
                          float* __restrict__ sX, float* __restrict__ sY,
                          float* __restrict__ T1, unsigned int* __restrict__ cnt,
                          float* __restrict__ out) {
  __shared__ __align__(16) __bf16 Ax[BM * BK];
  __shared__ __align__(16) __bf16 Bx[BM * BK];
  __shared__ __align__(16) __bf16 Ay[BM * BK];
  __shared__ __align__(16) __bf16 By[BM * BK];

  // triangular decode: blockIdx.x -> (bI, bJ) with bJ >= bI
  int idx = blockIdx.x;
  const float nf = (float)NB + 0.5f;
  int bI = (int)(nf - sqrtf(nf * nf - 2.0f * (float)idx));
  if (bI < 0) bI = 0;
  if (bI >= NB) bI = NB - 1;
  while (bI * NB - bI * (bI - 1) / 2 > idx) --bI;
  while ((bI + 1) * NB - (bI + 1) * bI / 2 <= idx) ++bI;
  const int bJ = bI + (idx - (bI * NB - bI * (bI - 1) / 2));
  const bool offdiag = (bI != bJ);

  const int tid = threadIdx.x;
  const int lane = tid & 63, wave = tid >> 6;
  const int wm = wave >> 1, wn = wave & 1;   // 2x2 wave grid, each wave 32x32
  const int quad = lane >> 4, cl = lane & 15;

  const __bf16* Xb = (const __bf16*)Xbh;
  const __bf16* Yb = (const __bf16*)Ybh;
  const __bf16* gAx = Xb + (size_t)bI * BM * D;
  const __bf16* gBx = Xb + (size_t)bJ * BM * D;
  const __bf16* gAy = Yb + (size_t)bI * BM * D;
  const __bf16* gBy = Yb + (size_t)bJ * BM * D;

  floatx4 accX[2][2];
  floatx4 accY[2][2];
#pragma unroll
  for (int i = 0; i < 2; ++i)
#pragma unroll
    for (int j = 0; j < 2; ++j) {
      accX[i][j] = (floatx4){0.f, 0.f, 0.f, 0.f};
      accY[i][j] = (floatx4){0.f, 0.f, 0.f, 0.f};
    }

  // staging: each buffer is 64x32 bf16 = 4KB = 256 16B-chunks, one per thread.
  // chunk c: row = c>>2, col8 = (c&3)*8; LDS byte dest = c*16 (lane-contiguous)
  const int c_r = tid >> 2;
  const int c_col = (tid & 3) * 8;
  const int c_loff = tid * 8;

  for (int kt = 0; kt < KITERS; ++kt) {
    const int k0 = kt * BK;
    __syncthreads();  // protect LDS from prior iteration's readers
    const size_t goff = (size_t)c_r * D + k0 + c_col;
    stage16(gAx + goff, &Ax[c_loff]);
    stage16(gBx + goff, &Bx[c_loff]);
    stage16(gAy + goff, &Ay[c_loff]);
    stage16(gBy + goff, &By[c_loff]);
    __syncthreads();  // drains vmcnt for global_load_lds

    bf16x8 bxf[2], byf[2];
#pragma unroll
    for (int ni = 0; ni < 2; ++ni) {
      const int rr = wn * 32 + ni * 16 + cl;
      const int off = rr * BK + quad * 8;
      bxf[ni] = *(const bf16x8*)&Bx[off];
      byf[ni] = *(const bf16x8*)&By[off];
    }
#pragma unroll
    for (int mi = 0; mi < 2; ++mi) {
      const int rr = wm * 32 + mi * 16 + cl;
      const int off = rr * BK + quad * 8;
      bf16x8 axf = *(const bf16x8*)&Ax[off];
      bf16x8 ayf = *(const bf16x8*)&Ay[off];
#pragma unroll
      for (int ni = 0; ni < 2; ++ni) {
        accX[mi][ni] = __builtin_amdgcn_mfma_f32_16x16x32_bf16(axf, bxf[ni], accX[mi][ni], 0, 0, 0);
        accY[mi][ni] = __builtin_amdgcn_mfma_f32_16x16x32_bf16(ayf, byf[ni], accY[mi][ni], 0, 0, 0);
      }
    }
  }

  // ---- epilogue ----
  // C/D layout (m89-verified): col = lane&15, row = (lane>>4)*4 + reg
  const int Ib = bI * BM + wm * 32;
  const int Jb = bJ * BM + wn * 32;
  float t1l = 0.f;
  float rx[2][4], ry[2][4];  // [mi][reg] row-sum partials over this wave's 32 cols
  float cx[2], cy[2];        // [ni] col-sum partials over this lane's 8 rows
#pragma unroll
  for (int mi = 0; mi < 2; ++mi)
#pragma unroll
    for (int r = 0; r < 4; ++r) { rx[mi][r] = 0.f; ry[mi][r] = 0.f; }
#pragma unroll
  for (int ni = 0; ni < 2; ++ni) { cx[ni] = 0.f; cy[ni] = 0.f; }

#pragma unroll
  for (int mi = 0; mi < 2; ++mi) {
    const int ig0 = Ib + mi * 16 + quad * 4;
    float sxi[4], syi[4];
#pragma unroll
    for (int r = 0; r < 4; ++r) { sxi[r] = sqX[ig0 + r]; syi[r] = sqY[ig0 + r]; }
#pragma unroll
    for (int ni = 0; ni < 2; ++ni) {
      const int jg = Jb + ni * 16 + cl;
      const float sxj = sqX[jg];
      const float syj = sqY[jg];
#pragma unroll
      for (int r = 0; r < 4; ++r) {
        const int ig = ig0 + r;
        float kx, ky;
        if (ig == jg) {
          kx = 1.f; ky = 1.f;  // exact diagonal: d2 == 0 mathematically
        } else {
          kx = __expf(-0.5f * (sxi[r] + sxj - 2.f * accX[mi][ni][r]));
          ky = __expf(-0.5f * (syi[r] + syj - 2.f * accY[mi][ni][r]));
        }
        t1l += kx * ky;
        rx[mi][r] += kx;
        ry[mi][r] += ky;
        cx[ni] += kx;
        cy[ni] += ky;
      }
    }
  }

  // row sums: reduce across the 16 columns (lanes cl=0..15 within each quad)
#pragma unroll
  for (int mi = 0; mi < 2; ++mi)
#pragma unroll
    for (int r = 0; r < 4; ++r) {
      float vx = rx[mi][r], vy = ry[mi][r];
#pragma unroll
      for (int mm = 1; mm < 16; mm <<= 1) {
        vx += __shfl_xor(vx, mm, 16);
        vy += __shfl_xor(vy, mm, 16);
      }
      rx[mi][r] = vx; ry[mi][r] = vy;
    }
  if (cl == 0) {
#pragma unroll
    for (int mi = 0; mi < 2; ++mi)
#pragma unroll
      for (int r = 0; r < 4; ++r) {
        const int row = Ib + mi * 16 + quad * 4 + r;
        atomicAdd(&sX[row], rx[mi][r]);
        atomicAdd(&sY[row], ry[mi][r]);
      }
  }

  // col sums (off-diagonal only): reduce across quads, quad 0 holds totals
  if (offdiag) {
#pragma unroll
    for (int ni = 0; ni < 2; ++ni) {
      float vx = cx[ni], vy = cy[ni];
      vx += __shfl_xor(vx, 16, 64); vy += __shfl_xor(vy, 16, 64);
      vx += __shfl_xor(vx, 32, 64); vy += __shfl_xor(vy, 32, 64);
      if (quad == 0) {
        const int col = Jb + ni * 16 + cl;
        atomicAdd(&sX[col], vx);
        atomicAdd(&sY[col], vy);
      }
    }
  }

  // block contribution to T1 (off-diagonal tiles count twice by symmetry)
  t1l *= offdiag ? 2.f : 1.f;
#pragma unroll
  for (int mm = 1; mm < 64; mm <<= 1) t1l += __shfl_xor(t1l, mm, 64);
  __shared__ float tred[4];
  if (lane == 0) tred[wave] = t1l;
  __syncthreads();
  if (tid == 0) atomicAdd(T1, tred[0] + tred[1] + tred[2] + tred[3]);

  // ---- completion-counter fused finalization (last block) ----
  __threadfence();   // make this thread's atomics visible device-wide
  __syncthreads();   // all threads' fences done before counter bump
  __shared__ int is_last;
  if (tid == 0) {
    unsigned int old = __hip_atomic_fetch_add(cnt, 1u, __ATOMIC_ACQ_REL,
                                              __HIP_MEMORY_SCOPE_AGENT);
    is_last = (old == (unsigned int)(NBLK - 1));
  }
  __syncthreads();
  if (is_last) {
    float dp = 0.f, sa = 0.f, sb = 0.f;
    for (int i = tid; i < N; i += 256) {
      float a = __hip_atomic_load(&sX[i], __ATOMIC_RELAXED, __HIP_MEMORY_SCOPE_AGENT);
      float b = __hip_atomic_load(&sY[i], __ATOMIC_RELAXED, __HIP_MEMORY_SCOPE_AGENT);
      dp += a * b; sa += a; sb += b;
    }
#pragma unroll
    for (int mm = 1; mm < 64; mm <<= 1) {
      dp += __shfl_xor(dp, mm, 64);
      sa += __shfl_xor(sa, mm, 64);
      sb += __shfl_xor(sb, mm, 64);
    }
    __shared__ float r0[4], r1[4], r2[4];
    if (lane == 0) { r0[wave] = dp; r1[wave] = sa; r2[wave] = sb; }
    __syncthreads();
    if (tid == 0) {
      dp = r0[0] + r0[1] + r0[2] + r0[3];
      sa = r1[0] + r1[1] + r1[2] + r1[3];
      sb = r2[0] + r2[1] + r2[2] + r2[3];
      float t1 = __hip_atomic_load(T1, __ATOMIC_RELAXED, __HIP_MEMORY_SCOPE_AGENT);
      const float n = (float)N;
      const float total = t1 - (2.f / n) * dp + (sa * sb) / (n * n);
      out[0] = total / ((n - 1.f) * (n - 1.f));
    }
  }
}

}  // namespace

extern "C" void kernel_launch(void* const* d_in, const int* in_sizes, int n_in,
                              void* d_out, int out_size, void* d_ws, size_t ws_size,
                              hipStream_t stream) {
  const float* X = (const float*)d_in[0];
  const float* Y = (const float*)d_in[1];
  char* ws = (char*)d_ws;
  if (ws_size < WS_NEED) return;

  unsigned short* Xb = (unsigned short*)(ws + OFF_XB);
  unsigned short* Yb = (unsigned short*)(ws + OFF_YB);
  float* sqX = (float*)(ws + OFF_SQX);
  float* sqY = (float*)(ws + OFF_SQY);
  float* sX  = (float*)(ws + OFF_SX);
  float* sY  = (float*)(ws + OFF_SY);
  float* T1  = (float*)(ws + OFF_T1);
  unsigned int* cnt = (unsigned int*)(ws + OFF_CNT);
  float* out = (float*)d_out;

  prep_kernel<<<dim3(N / 4, 2), 256, 0, stream>>>(X, Y, Xb, Yb, sqX, sqY,
                                                  sX, sY, T1, cnt);
  hsic_main<<<NBLK, 256, 0, stream>>>((const __hip_bfloat16*)Xb, (const __hip_bfloat16*)Yb,
                                      sqX, sqY, sX, sY, T1, cnt, out);
}

// Round 4
// 239.893 us; speedup vs baseline: 1.4200x; 1.4200x over previous
//
#include <hip/hip_runtime.h>
#include <hip/hip_bf16.h>

namespace {

constexpr int N = 4096;
constexpr int D = 512;
constexpr int BM = 128;   // block tile (rows == cols)
constexpr int BK = 32;    // K-step per iteration
constexpr int KITERS = D / BK;  // 16
constexpr int NB = N / BM;      // 32 block-rows
constexpr int NBLK = NB * (NB + 1) / 2;  // 528 upper-tri blocks

// workspace layout (bytes)
constexpr size_t OFF_XB  = 0;                          // bf16 X  [N*D]
constexpr size_t OFF_YB  = (size_t)N * D * 2;          // bf16 Y  [N*D]
constexpr size_t OFF_SQX = OFF_YB + (size_t)N * D * 2; // fp32 ||x_i||^2 [N]
constexpr size_t OFF_SQY = OFF_SQX + (size_t)N * 4;
constexpr size_t OFF_SX  = OFF_SQY + (size_t)N * 4;    // fp32 row sums KX [N]  (zeroed by prep)
constexpr size_t OFF_SY  = OFF_SX + (size_t)N * 4;     // fp32 row sums KY [N]  (zeroed by prep)
constexpr size_t OFF_T1  = OFF_SY + (size_t)N * 4;     // fp32 scalar sum(KX*KY) (zeroed by prep)
constexpr size_t WS_NEED = OFF_T1 + 4;

// exp(-0.5*d2) is EXACTLY +0.0f in fp32 when 0.5*d2 > 150*ln2 ~ 104; use a
// conservative threshold d2 >= 240 (0.5*240 = 120). Skipping those entries
// adds exact zeros -> bit-identical result for any input.
constexpr float D2_SKIP = 240.f;

typedef __attribute__((ext_vector_type(8))) __bf16 bf16x8;
typedef __attribute__((ext_vector_type(4))) float floatx4;

__device__ inline void stage16(const void* g, void* l) {
  __builtin_amdgcn_global_load_lds(
      (const __attribute__((address_space(1))) unsigned int*)g,
      (__attribute__((address_space(3))) unsigned int*)l, 16, 0, 0);
}

__device__ inline unsigned short f2bf(float f) {
  __hip_bfloat16 h = __float2bfloat16(f);
  return __builtin_bit_cast(unsigned short, h);
}

// fp32 -> bf16 conversion + row squared norms. One wave per row (float4 loads,
// ushort4 stores), 4 rows per block, grid.y selects X vs Y.
// Also zeroes sX/sY/T1 for this call (ws is re-poisoned before every launch).
__global__ void prep_kernel(const float* __restrict__ X, const float* __restrict__ Y,
                            unsigned short* __restrict__ Xb, unsigned short* __restrict__ Yb,
                            float* __restrict__ sqX, float* __restrict__ sqY,
                            float* __restrict__ sX, float* __restrict__ sY,
                            float* __restrict__ T1) {
  const int wave = threadIdx.x >> 6, lane = threadIdx.x & 63;
  const int row = blockIdx.x * 4 + wave;
  const int m = blockIdx.y;
  const float* __restrict__ src = m ? Y : X;
  unsigned short* __restrict__ dst = m ? Yb : Xb;
  float* __restrict__ dsq = m ? sqY : sqX;

  // zero accumulators: each (block,y) pair covers 4 entries of sX or sY
  if (threadIdx.x < 4) {
    float* z = m ? sY : sX;
    z[blockIdx.x * 4 + threadIdx.x] = 0.f;
  }
  if (blockIdx.x == 0 && m == 0 && threadIdx.x == 0) *T1 = 0.f;

  const float4* s4 = (const float4*)(src + (size_t)row * D);
  ushort4* d4 = (ushort4*)(dst + (size_t)row * D);
  float acc = 0.f;
#pragma unroll
  for (int h = 0; h < 2; ++h) {
    float4 v = s4[lane + h * 64];
    acc += v.x * v.x + v.y * v.y + v.z * v.z + v.w * v.w;
    ushort4 o;
    o.x = f2bf(v.x); o.y = f2bf(v.y); o.z = f2bf(v.z); o.w = f2bf(v.w);
    d4[lane + h * 64] = o;
  }
#pragma unroll
  for (int mm = 32; mm >= 1; mm >>= 1) acc += __shfl_xor(acc, mm, 64);
  if (lane == 0) dsq[row] = acc;
}

// Upper-triangular fused Gram+RBF+reductions, 128x128 tiles, 2x2 waves of
// 64x64. Off-diag tiles: T1 weight 2, col sums feed rows J by symmetry.
// Epilogue has a wave-uniform underflow fast-path (see D2_SKIP).
// NO device fences anywhere (R3 post-mortem: agent-release fence per block
// caused an L2 writeback/invalidate storm, 5x regression).
__launch_bounds__(256, 4)
__global__ void hsic_main(const __hip_bfloat16* __restrict__ Xbh,
                          const __hip_bfloat16* __restrict__ Ybh,
                          const float* __restrict__ sqX, const float* __restrict__ sqY,
                          float* __restrict__ sX, float* __restrict__ sY,
                          float* __restrict__ T1) {
  __shared__ __align__(16) __bf16 Ax[BM * BK];
  __shared__ __align__(16) __bf16 Bx[BM * BK];
  __shared__ __align__(16) __bf16 Ay[BM * BK];
  __shared__ __align__(16) __bf16 By[BM * BK];

  // triangular decode: blockIdx.x -> (bI, bJ) with bJ >= bI
  int idx = blockIdx.x;
  const float nf = (float)NB + 0.5f;
  int bI = (int)(nf - sqrtf(nf * nf - 2.0f * (float)idx));
  if (bI < 0) bI = 0;
  if (bI >= NB) bI = NB - 1;
  while (bI * NB - bI * (bI - 1) / 2 > idx) --bI;
  while ((bI + 1) * NB - (bI + 1) * bI / 2 <= idx) ++bI;
  const int bJ = bI + (idx - (bI * NB - bI * (bI - 1) / 2));
  const bool offdiag = (bI != bJ);

  const int tid = threadIdx.x;
  const int lane = tid & 63, wave = tid >> 6;
  const int wm = wave >> 1, wn = wave & 1;   // 2x2 wave grid, each wave 64x64
  const int quad = lane >> 4, cl = lane & 15;

  const __bf16* Xb = (const __bf16*)Xbh;
  const __bf16* Yb = (const __bf16*)Ybh;
  const __bf16* gAx = Xb + (size_t)bI * BM * D;
  const __bf16* gBx = Xb + (size_t)bJ * BM * D;
  const __bf16* gAy = Yb + (size_t)bI * BM * D;
  const __bf16* gBy = Yb + (size_t)bJ * BM * D;

  floatx4 accX[4][4];
  floatx4 accY[4][4];
#pragma unroll
  for (int i = 0; i < 4; ++i)
#pragma unroll
    for (int j = 0; j < 4; ++j) {
      accX[i][j] = (floatx4){0.f, 0.f, 0.f, 0.f};
      accY[i][j] = (floatx4){0.f, 0.f, 0.f, 0.f};
    }

  for (int kt = 0; kt < KITERS; ++kt) {
    const int k0 = kt * BK;
    __syncthreads();  // protect LDS from prior iteration's readers
#pragma unroll
    for (int h = 0; h < 2; ++h) {
      const int c = tid + h * 256;
      const int r = c >> 2;
      const int col = (c & 3) * 8;
      const size_t goff = (size_t)r * D + k0 + col;
      const int loff = c * 8;
      stage16(gAx + goff, &Ax[loff]);
      stage16(gBx + goff, &Bx[loff]);
      stage16(gAy + goff, &Ay[loff]);
      stage16(gBy + goff, &By[loff]);
    }
    __syncthreads();  // drains vmcnt for global_load_lds

    bf16x8 bxf[4], byf[4];
#pragma unroll
    for (int ni = 0; ni < 4; ++ni) {
      const int rr = wn * 64 + ni * 16 + cl;
      const int off = rr * BK + quad * 8;
      bxf[ni] = *(const bf16x8*)&Bx[off];
      byf[ni] = *(const bf16x8*)&By[off];
    }
#pragma unroll
    for (int mi = 0; mi < 4; ++mi) {
      const int rr = wm * 64 + mi * 16 + cl;
      const int off = rr * BK + quad * 8;
      bf16x8 axf = *(const bf16x8*)&Ax[off];
      bf16x8 ayf = *(const bf16x8*)&Ay[off];
#pragma unroll
      for (int ni = 0; ni < 4; ++ni) {
        accX[mi][ni] = __builtin_amdgcn_mfma_f32_16x16x32_bf16(axf, bxf[ni], accX[mi][ni], 0, 0, 0);
        accY[mi][ni] = __builtin_amdgcn_mfma_f32_16x16x32_bf16(ayf, byf[ni], accY[mi][ni], 0, 0, 0);
      }
    }
  }

  // ---- epilogue ----
  // C/D layout (m89-verified): col = lane&15, row = (lane>>4)*4 + reg
  const int Ib = bI * BM + wm * 64;
  const int Jb = bJ * BM + wn * 64;
  float t1l = 0.f;
  float rx[4][4], ry[4][4];  // [mi][reg] row-sum partials over this wave's 64 cols
  float cx[4], cy[4];        // [ni] col-sum partials over this lane's 16 rows
#pragma unroll
  for (int mi = 0; mi < 4; ++mi)
#pragma unroll
    for (int r = 0; r < 4; ++r) { rx[mi][r] = 0.f; ry[mi][r] = 0.f; }
#pragma unroll
  for (int ni = 0; ni < 4; ++ni) { cx[ni] = 0.f; cy[ni] = 0.f; }

  bool wave_any = false;  // wave-uniform after __any-gated updates

#pragma unroll
  for (int mi = 0; mi < 4; ++mi) {
    const int ig0 = Ib + mi * 16 + quad * 4;
    float sxi[4], syi[4];
#pragma unroll
    for (int r = 0; r < 4; ++r) { sxi[r] = sqX[ig0 + r]; syi[r] = sqY[ig0 + r]; }
#pragma unroll
    for (int ni = 0; ni < 4; ++ni) {
      const int jg = Jb + ni * 16 + cl;
      const float sxj = sqX[jg];
      const float syj = sqY[jg];
      float d2x[4], d2y[4];
      bool lflag = false;
#pragma unroll
      for (int r = 0; r < 4; ++r) {
        const int ig = ig0 + r;
        d2x[r] = sxi[r] + sxj - 2.f * accX[mi][ni][r];
        d2y[r] = syi[r] + syj - 2.f * accY[mi][ni][r];
        lflag |= (d2x[r] < D2_SKIP) | (d2y[r] < D2_SKIP) | (ig == jg);
      }
      if (__any(lflag)) {   // wave-uniform: skip means all contributions == +0.0f
        wave_any = true;
#pragma unroll
        for (int r = 0; r < 4; ++r) {
          const int ig = ig0 + r;
          float kx, ky;
          if (ig == jg) {
            kx = 1.f; ky = 1.f;  // exact diagonal: d2 == 0 mathematically
          } else {
            kx = __expf(-0.5f * d2x[r]);
            ky = __expf(-0.5f * d2y[r]);
          }
          t1l += kx * ky;
          rx[mi][r] += kx;
          ry[mi][r] += ky;
          cx[ni] += kx;
          cy[ni] += ky;
        }
      }
    }
  }

  if (wave_any) {
    // row sums: reduce across the 16 columns (lanes cl=0..15 within each quad)
#pragma unroll
    for (int mi = 0; mi < 4; ++mi)
#pragma unroll
      for (int r = 0; r < 4; ++r) {
        float vx = rx[mi][r], vy = ry[mi][r];
#pragma unroll
        for (int mm = 1; mm < 16; mm <<= 1) {
          vx += __shfl_xor(vx, mm, 16);
          vy += __shfl_xor(vy, mm, 16);
        }
        rx[mi][r] = vx; ry[mi][r] = vy;
      }
    if (cl == 0) {
#pragma unroll
      for (int mi = 0; mi < 4; ++mi)
#pragma unroll
        for (int r = 0; r < 4; ++r) {
          const int row = Ib + mi * 16 + quad * 4 + r;
          atomicAdd(&sX[row], rx[mi][r]);
          atomicAdd(&sY[row], ry[mi][r]);
        }
    }

    // col sums (off-diagonal only): reduce across quads, quad 0 holds totals
    if (offdiag) {
#pragma unroll
      for (int ni = 0; ni < 4; ++ni) {
        float vx = cx[ni], vy = cy[ni];
        vx += __shfl_xor(vx, 16, 64); vy += __shfl_xor(vy, 16, 64);
        vx += __shfl_xor(vx, 32, 64); vy += __shfl_xor(vy, 32, 64);
        if (quad == 0) {
          const int col = Jb + ni * 16 + cl;
          atomicAdd(&sX[col], vx);
          atomicAdd(&sY[col], vy);
        }
      }
    }

    // T1 wave reduction (off-diagonal tiles count twice by symmetry)
    t1l *= offdiag ? 2.f : 1.f;
#pragma unroll
    for (int mm = 1; mm < 64; mm <<= 1) t1l += __shfl_xor(t1l, mm, 64);
  }
  // if !wave_any, t1l == 0 uniformly; no reduction needed
  __shared__ float tred[4];
  if (lane == 0) tred[wave] = t1l;
  __syncthreads();
  if (tid == 0) {
    const float t = tred[0] + tred[1] + tred[2] + tred[3];
    if (t != 0.f) atomicAdd(T1, t);
  }
}

// hsic = (T1 - (2/n) sum sX_i sY_i + (SX*SY)/n^2) / (n-1)^2
__global__ void final_kernel(const float* __restrict__ sX, const float* __restrict__ sY,
                             const float* __restrict__ T1, float* __restrict__ out) {
  const int tid = threadIdx.x;
  float dp = 0.f, sa = 0.f, sb = 0.f;
  for (int i = tid; i < N; i += 256) {
    float a = sX[i], b = sY[i];
    dp += a * b; sa += a; sb += b;
  }
#pragma unroll
  for (int mm = 1; mm < 64; mm <<= 1) {
    dp += __shfl_xor(dp, mm, 64);
    sa += __shfl_xor(sa, mm, 64);
    sb += __shfl_xor(sb, mm, 64);
  }
  __shared__ float r0[4], r1[4], r2[4];
  if ((tid & 63) == 0) { int w = tid >> 6; r0[w] = dp; r1[w] = sa; r2[w] = sb; }
  __syncthreads();
  if (tid == 0) {
    dp = r0[0] + r0[1] + r0[2] + r0[3];
    sa = r1[0] + r1[1] + r1[2] + r1[3];
    sb = r2[0] + r2[1] + r2[2] + r2[3];
    const float n = (float)N;
    const float total = T1[0] - (2.f / n) * dp + (sa * sb) / (n * n);
    out[0] = total / ((n - 1.f) * (n - 1.f));
  }
}

}  // namespace

extern "C" void kernel_launch(void* const* d_in, const int* in_sizes, int n_in,
                              void* d_out, int out_size, void* d_ws, size_t ws_size,
                              hipStream_t stream) {
  const float* X = (const float*)d_in[0];
  const float* Y = (const float*)d_in[1];
  char* ws = (char*)d_ws;
  if (ws_size < WS_NEED) return;

  unsigned short* Xb = (unsigned short*)(ws + OFF_XB);
  unsigned short* Yb = (unsigned short*)(ws + OFF_YB);
  float* sqX = (float*)(ws + OFF_SQX);
  float* sqY = (float*)(ws + OFF_SQY);
  float* sX  = (float*)(ws + OFF_SX);
  float* sY  = (float*)(ws + OFF_SY);
  float* T1  = (float*)(ws + OFF_T1);
  float* out = (float*)d_out;

  prep_kernel<<<dim3(N / 4, 2), 256, 0, stream>>>(X, Y, Xb, Yb, sqX, sqY, sX, sY, T1);
  hsic_main<<<NBLK, 256, 0, stream>>>((const __hip_bfloat16*)Xb, (const __hip_bfloat16*)Yb,
                                      sqX, sqY, sX, sY, T1);
  final_kernel<<<1, 256, 0, stream>>>(sX, sY, T1, out);
}

// Round 5
// 112.821 us; speedup vs baseline: 3.0193x; 2.1263x over previous
//
#include <hip/hip_runtime.h>
#include <hip/hip_bf16.h>

namespace {

constexpr int N = 4096;
constexpr int D = 512;
constexpr int BM = 128;   // block tile (rows == cols)
constexpr int BK = 32;    // K-step per iteration
constexpr int KITERS = D / BK;  // 16
constexpr int NB = N / BM;      // 32 block-rows
constexpr int NBLK = NB * (NB + 1) / 2;  // 528 upper-tri blocks
constexpr int TILE = BM * BK;   // elements per staged tile (4K elems, 8 KB)

// workspace layout (bytes)
constexpr size_t OFF_XB  = 0;                          // bf16 X  [N*D]
constexpr size_t OFF_YB  = (size_t)N * D * 2;          // bf16 Y  [N*D]
constexpr size_t OFF_SQX = OFF_YB + (size_t)N * D * 2; // fp32 ||x_i||^2 [N]
constexpr size_t OFF_SQY = OFF_SQX + (size_t)N * 4;
constexpr size_t OFF_SX  = OFF_SQY + (size_t)N * 4;    // fp32 row sums KX [N]  (zeroed by prep)
constexpr size_t OFF_SY  = OFF_SX + (size_t)N * 4;     // fp32 row sums KY [N]  (zeroed by prep)
constexpr size_t OFF_T1  = OFF_SY + (size_t)N * 4;     // fp32 scalar sum(KX*KY) (zeroed by prep)
constexpr size_t WS_NEED = OFF_T1 + 4;

// exp(-0.5*d2) is EXACTLY +0.0f in fp32 when 0.5*d2 > 150*ln2 ~ 104; use a
// conservative threshold d2 >= 240. Skipping those entries adds exact zeros
// -> bit-identical result for any input.
constexpr float D2_SKIP = 240.f;

typedef __attribute__((ext_vector_type(8))) __bf16 bf16x8;
typedef __attribute__((ext_vector_type(4))) float floatx4;

__device__ inline void stage16(const void* g, void* l) {
  __builtin_amdgcn_global_load_lds(
      (const __attribute__((address_space(1))) unsigned int*)g,
      (__attribute__((address_space(3))) unsigned int*)l, 16, 0, 0);
}

__device__ inline unsigned short f2bf(float f) {
  __hip_bfloat16 h = __float2bfloat16(f);
  return __builtin_bit_cast(unsigned short, h);
}

// fp32 -> bf16 conversion + row squared norms. One wave per row (float4 loads,
// ushort4 stores), 4 rows per block, grid.y selects X vs Y.
// Also zeroes sX/sY/T1 for this call (ws is re-poisoned before every launch).
__global__ void prep_kernel(const float* __restrict__ X, const float* __restrict__ Y,
                            unsigned short* __restrict__ Xb, unsigned short* __restrict__ Yb,
                            float* __restrict__ sqX, float* __restrict__ sqY,
                            float* __restrict__ sX, float* __restrict__ sY,
                            float* __restrict__ T1) {
  const int wave = threadIdx.x >> 6, lane = threadIdx.x & 63;
  const int row = blockIdx.x * 4 + wave;
  const int m = blockIdx.y;
  const float* __restrict__ src = m ? Y : X;
  unsigned short* __restrict__ dst = m ? Yb : Xb;
  float* __restrict__ dsq = m ? sqY : sqX;

  // zero accumulators: each (block,y) pair covers 4 entries of sX or sY
  if (threadIdx.x < 4) {
    float* z = m ? sY : sX;
    z[blockIdx.x * 4 + threadIdx.x] = 0.f;
  }
  if (blockIdx.x == 0 && m == 0 && threadIdx.x == 0) *T1 = 0.f;

  const float4* s4 = (const float4*)(src + (size_t)row * D);
  ushort4* d4 = (ushort4*)(dst + (size_t)row * D);
  float acc = 0.f;
#pragma unroll
  for (int h = 0; h < 2; ++h) {
    float4 v = s4[lane + h * 64];
    acc += v.x * v.x + v.y * v.y + v.z * v.z + v.w * v.w;
    ushort4 o;
    o.x = f2bf(v.x); o.y = f2bf(v.y); o.z = f2bf(v.z); o.w = f2bf(v.w);
    d4[lane + h * 64] = o;
  }
#pragma unroll
  for (int mm = 32; mm >= 1; mm >>= 1) acc += __shfl_xor(acc, mm, 64);
  if (lane == 0) dsq[row] = acc;
}

// Upper-triangular fused Gram+RBF+reductions, 128x128 tiles, 2x2 waves of
// 64x64. DOUBLE-BUFFERED K-loop: one barrier per iter; prefetch of tile k+1
// is issued right after the barrier and flies during compute of tile k, so
// the compiler's vmcnt(0)-before-barrier drains it exactly when iter k+1
// needs it. Only iter 0 pays full staging latency. (R2's single-buffer
// 2-barrier loop was per-block latency-bound at ~2 blocks/CU.)
// NO device fences (R3: per-block agent fence = L2 writeback storm, 5x).
// launch_bounds must stay (256,2): (256,4) forced 128-VGPR cap -> 326 MB of
// scratch spill traffic (R4).
__launch_bounds__(256, 2)
__global__ void hsic_main(const __hip_bfloat16* __restrict__ Xbh,
                          const __hip_bfloat16* __restrict__ Ybh,
                          const float* __restrict__ sqX, const float* __restrict__ sqY,
                          float* __restrict__ sX, float* __restrict__ sY,
                          float* __restrict__ T1) {
  // [buf][tile]: tiles Ax, Bx, Ay, By each BM*BK elements; 64 KB total
  __shared__ __align__(16) __bf16 smem[2][4 * TILE];

  // triangular decode: blockIdx.x -> (bI, bJ) with bJ >= bI
  int idx = blockIdx.x;
  const float nf = (float)NB + 0.5f;
  int bI = (int)(nf - sqrtf(nf * nf - 2.0f * (float)idx));
  if (bI < 0) bI = 0;
  if (bI >= NB) bI = NB - 1;
  while (bI * NB - bI * (bI - 1) / 2 > idx) --bI;
  while ((bI + 1) * NB - (bI + 1) * bI / 2 <= idx) ++bI;
  const int bJ = bI + (idx - (bI * NB - bI * (bI - 1) / 2));
  const bool offdiag = (bI != bJ);

  const int tid = threadIdx.x;
  const int lane = tid & 63, wave = tid >> 6;
  const int wm = wave >> 1, wn = wave & 1;   // 2x2 wave grid, each wave 64x64
  const int quad = lane >> 4, cl = lane & 15;

  const __bf16* Xb = (const __bf16*)Xbh;
  const __bf16* Yb = (const __bf16*)Ybh;
  const __bf16* gAx = Xb + (size_t)bI * BM * D;
  const __bf16* gBx = Xb + (size_t)bJ * BM * D;
  const __bf16* gAy = Yb + (size_t)bI * BM * D;
  const __bf16* gBy = Yb + (size_t)bJ * BM * D;

  floatx4 accX[4][4];
  floatx4 accY[4][4];
#pragma unroll
  for (int i = 0; i < 4; ++i)
#pragma unroll
    for (int j = 0; j < 4; ++j) {
      accX[i][j] = (floatx4){0.f, 0.f, 0.f, 0.f};
      accY[i][j] = (floatx4){0.f, 0.f, 0.f, 0.f};
    }

  // staging: each tile is 512 16B-chunks; 256 threads x 2 chunks.
  // chunk c: row = c>>2, col8 = (c&3)*8; LDS elem dest = c*8 (lane-contiguous)
  auto stage_all = [&](int kt, int buf) {
    const int k0 = kt * BK;
#pragma unroll
    for (int h = 0; h < 2; ++h) {
      const int c = tid + h * 256;
      const int r = c >> 2;
      const int col = (c & 3) * 8;
      const size_t goff = (size_t)r * D + k0 + col;
      const int loff = c * 8;
      stage16(gAx + goff, &smem[buf][0 * TILE + loff]);
      stage16(gBx + goff, &smem[buf][1 * TILE + loff]);
      stage16(gAy + goff, &smem[buf][2 * TILE + loff]);
      stage16(gBy + goff, &smem[buf][3 * TILE + loff]);
    }
  };

  stage_all(0, 0);

  for (int kt = 0; kt < KITERS; ++kt) {
    const int buf = kt & 1;
    // drains stage(kt) [vmcnt(0) emitted before s_barrier]; also separates
    // prior reads of buf^1 (iter kt-1) from the prefetch writes below
    __syncthreads();
    if (kt + 1 < KITERS) stage_all(kt + 1, buf ^ 1);

    const __bf16* Ax = &smem[buf][0 * TILE];
    const __bf16* Bx = &smem[buf][1 * TILE];
    const __bf16* Ay = &smem[buf][2 * TILE];
    const __bf16* By = &smem[buf][3 * TILE];

    bf16x8 bxf[4], byf[4];
#pragma unroll
    for (int ni = 0; ni < 4; ++ni) {
      const int rr = wn * 64 + ni * 16 + cl;
      const int off = rr * BK + quad * 8;
      bxf[ni] = *(const bf16x8*)&Bx[off];
      byf[ni] = *(const bf16x8*)&By[off];
    }
#pragma unroll
    for (int mi = 0; mi < 4; ++mi) {
      const int rr = wm * 64 + mi * 16 + cl;
      const int off = rr * BK + quad * 8;
      bf16x8 axf = *(const bf16x8*)&Ax[off];
      bf16x8 ayf = *(const bf16x8*)&Ay[off];
#pragma unroll
      for (int ni = 0; ni < 4; ++ni) {
        accX[mi][ni] = __builtin_amdgcn_mfma_f32_16x16x32_bf16(axf, bxf[ni], accX[mi][ni], 0, 0, 0);
        accY[mi][ni] = __builtin_amdgcn_mfma_f32_16x16x32_bf16(ayf, byf[ni], accY[mi][ni], 0, 0, 0);
      }
    }
  }

  // ---- epilogue ----
  // C/D layout (m89-verified): col = lane&15, row = (lane>>4)*4 + reg
  const int Ib = bI * BM + wm * 64;
  const int Jb = bJ * BM + wn * 64;
  float t1l = 0.f;
  float rx[4][4], ry[4][4];  // [mi][reg] row-sum partials over this wave's 64 cols
  float cx[4], cy[4];        // [ni] col-sum partials over this lane's 16 rows
#pragma unroll
  for (int mi = 0; mi < 4; ++mi)
#pragma unroll
    for (int r = 0; r < 4; ++r) { rx[mi][r] = 0.f; ry[mi][r] = 0.f; }
#pragma unroll
  for (int ni = 0; ni < 4; ++ni) { cx[ni] = 0.f; cy[ni] = 0.f; }

  bool wave_any = false;  // wave-uniform after __any-gated updates

#pragma unroll
  for (int mi = 0; mi < 4; ++mi) {
    const int ig0 = Ib + mi * 16 + quad * 4;
    float sxi[4], syi[4];
#pragma unroll
    for (int r = 0; r < 4; ++r) { sxi[r] = sqX[ig0 + r]; syi[r] = sqY[ig0 + r]; }
#pragma unroll
    for (int ni = 0; ni < 4; ++ni) {
      const int jg = Jb + ni * 16 + cl;
      const float sxj = sqX[jg];
      const float syj = sqY[jg];
      float d2x[4], d2y[4];
      bool lflag = false;
#pragma unroll
      for (int r = 0; r < 4; ++r) {
        const int ig = ig0 + r;
        d2x[r] = sxi[r] + sxj - 2.f * accX[mi][ni][r];
        d2y[r] = syi[r] + syj - 2.f * accY[mi][ni][r];
        lflag |= (d2x[r] < D2_SKIP) | (d2y[r] < D2_SKIP) | (ig == jg);
      }
      if (__any(lflag)) {   // wave-uniform: skipped entries are all exactly +0.0f
        wave_any = true;
#pragma unroll
        for (int r = 0; r < 4; ++r) {
          const int ig = ig0 + r;
          float kx, ky;
          if (ig == jg) {
            kx = 1.f; ky = 1.f;  // exact diagonal: d2 == 0 mathematically
          } else {
            kx = __expf(-0.5f * d2x[r]);
            ky = __expf(-0.5f * d2y[r]);
          }
          t1l += kx * ky;
          rx[mi][r] += kx;
          ry[mi][r] += ky;
          cx[ni] += kx;
          cy[ni] += ky;
        }
      }
    }
  }

  if (wave_any) {
    // row sums: reduce across the 16 columns (lanes cl=0..15 within each quad)
#pragma unroll
    for (int mi = 0; mi < 4; ++mi)
#pragma unroll
      for (int r = 0; r < 4; ++r) {
        float vx = rx[mi][r], vy = ry[mi][r];
#pragma unroll
        for (int mm = 1; mm < 16; mm <<= 1) {
          vx += __shfl_xor(vx, mm, 16);
          vy += __shfl_xor(vy, mm, 16);
        }
        rx[mi][r] = vx; ry[mi][r] = vy;
      }
    if (cl == 0) {
#pragma unroll
      for (int mi = 0; mi < 4; ++mi)
#pragma unroll
        for (int r = 0; r < 4; ++r) {
          const int row = Ib + mi * 16 + quad * 4 + r;
          atomicAdd(&sX[row], rx[mi][r]);
          atomicAdd(&sY[row], ry[mi][r]);
        }
    }

    // col sums (off-diagonal only): reduce across quads, quad 0 holds totals
    if (offdiag) {
#pragma unroll
      for (int ni = 0; ni < 4; ++ni) {
        float vx = cx[ni], vy = cy[ni];
        vx += __shfl_xor(vx, 16, 64); vy += __shfl_xor(vy, 16, 64);
        vx += __shfl_xor(vx, 32, 64); vy += __shfl_xor(vy, 32, 64);
        if (quad == 0) {
          const int col = Jb + ni * 16 + cl;
          atomicAdd(&sX[col], vx);
          atomicAdd(&sY[col], vy);
        }
      }
    }

    // T1 wave reduction (off-diagonal tiles count twice by symmetry)
    t1l *= offdiag ? 2.f : 1.f;
#pragma unroll
    for (int mm = 1; mm < 64; mm <<= 1) t1l += __shfl_xor(t1l, mm, 64);
  }
  // if !wave_any, t1l == 0 uniformly; no reduction needed
  __shared__ float tred[4];
  if (lane == 0) tred[wave] = t1l;
  __syncthreads();
  if (tid == 0) {
    const float t = tred[0] + tred[1] + tred[2] + tred[3];
    if (t != 0.f) atomicAdd(T1, t);
  }
}

// hsic = (T1 - (2/n) sum sX_i sY_i + (SX*SY)/n^2) / (n-1)^2
__global__ void final_kernel(const float* __restrict__ sX, const float* __restrict__ sY,
                             const float* __restrict__ T1, float* __restrict__ out) {
  const int tid = threadIdx.x;
  float dp = 0.f, sa = 0.f, sb = 0.f;
  for (int i = tid; i < N; i += 256) {
    float a = sX[i], b = sY[i];
    dp += a * b; sa += a; sb += b;
  }
#pragma unroll
  for (int mm = 1; mm < 64; mm <<= 1) {
    dp += __shfl_xor(dp, mm, 64);
    sa += __shfl_xor(sa, mm, 64);
    sb += __shfl_xor(sb, mm, 64);
  }
  __shared__ float r0[4], r1[4], r2[4];
  if ((tid & 63) == 0) { int w = tid >> 6; r0[w] = dp; r1[w] = sa; r2[w] = sb; }
  __syncthreads();
  if (tid == 0) {
    dp = r0[0] + r0[1] + r0[2] + r0[3];
    sa = r1[0] + r1[1] + r1[2] + r1[3];
    sb = r2[0] + r2[1] + r2[2] + r2[3];
    const float n = (float)N;
    const float total = T1[0] - (2.f / n) * dp + (sa * sb) / (n * n);
    out[0] = total / ((n - 1.f) * (n - 1.f));
  }
}

}  // namespace

extern "C" void kernel_launch(void* const* d_in, const int* in_sizes, int n_in,
                              void* d_out, int out_size, void* d_ws, size_t ws_size,
                              hipStream_t stream) {
  const float* X = (const float*)d_in[0];
  const float* Y = (const float*)d_in[1];
  char* ws = (char*)d_ws;
  if (ws_size < WS_NEED) return;

  unsigned short* Xb = (unsigned short*)(ws + OFF_XB);
  unsigned short* Yb = (unsigned short*)(ws + OFF_YB);
  float* sqX = (float*)(ws + OFF_SQX);
  float* sqY = (float*)(ws + OFF_SQY);
  float* sX  = (float*)(ws + OFF_SX);
  float* sY  = (float*)(ws + OFF_SY);
  float* T1  = (float*)(ws + OFF_T1);
  float* out = (float*)d_out;

  prep_kernel<<<dim3(N / 4, 2), 256, 0, stream>>>(X, Y, Xb, Yb, sqX, sqY, sX, sY, T1);
  hsic_main<<<NBLK, 256, 0, stream>>>((const __hip_bfloat16*)Xb, (const __hip_bfloat16*)Yb,
                                      sqX, sqY, sX, sY, T1);
  final_kernel<<<1, 256, 0, stream>>>(sX, sY, T1, out);
}

// Round 6
// 110.255 us; speedup vs baseline: 3.0896x; 1.0233x over previous
//
#include <hip/hip_runtime.h>
#include <hip/hip_bf16.h>

namespace {

constexpr int N = 4096;
constexpr int D = 512;
constexpr int BM = 128;   // block tile (rows == cols)
constexpr int BK = 32;    // K-step per iteration
constexpr int KITERS = D / BK;  // 16
constexpr int NB = N / BM;      // 32 block-rows
constexpr int NBLK = NB * (NB + 1) / 2;  // 528 upper-tri blocks (= 8 * 66)
constexpr int TILE = BM * BK;   // elements per staged tile (4K elems, 8 KB)

// workspace layout (bytes)
constexpr size_t OFF_XB  = 0;                          // bf16 X  [N*D]
constexpr size_t OFF_YB  = (size_t)N * D * 2;          // bf16 Y  [N*D]
constexpr size_t OFF_SQX = OFF_YB + (size_t)N * D * 2; // fp32 ||x_i||^2 [N]
constexpr size_t OFF_SQY = OFF_SQX + (size_t)N * 4;
constexpr size_t OFF_SX  = OFF_SQY + (size_t)N * 4;    // fp32 row sums KX [N]  (zeroed by prep)
constexpr size_t OFF_SY  = OFF_SX + (size_t)N * 4;     // fp32 row sums KY [N]  (zeroed by prep)
constexpr size_t OFF_T1  = OFF_SY + (size_t)N * 4;     // fp32 scalar sum(KX*KY) (zeroed by prep)
constexpr size_t WS_NEED = OFF_T1 + 4;

// exp(-0.5*d2) is EXACTLY +0.0f in fp32 when 0.5*d2 > 150*ln2 ~ 104; use a
// conservative threshold d2 >= 240. Skipping those entries adds exact zeros
// -> bit-identical result for any input.
constexpr float D2_SKIP = 240.f;

typedef __attribute__((ext_vector_type(8))) __bf16 bf16x8;
typedef __attribute__((ext_vector_type(4))) float floatx4;

__device__ inline void stage16(const void* g, void* l) {
  __builtin_amdgcn_global_load_lds(
      (const __attribute__((address_space(1))) unsigned int*)g,
      (__attribute__((address_space(3))) unsigned int*)l, 16, 0, 0);
}

__device__ inline unsigned short f2bf(float f) {
  __hip_bfloat16 h = __float2bfloat16(f);
  return __builtin_bit_cast(unsigned short, h);
}

// fp32 -> bf16 conversion + row squared norms. One wave per row (float4 loads,
// ushort4 stores), 4 rows per block, grid.y selects X vs Y.
// Also zeroes sX/sY/T1 for this call (ws is re-poisoned before every launch).
__global__ void prep_kernel(const float* __restrict__ X, const float* __restrict__ Y,
                            unsigned short* __restrict__ Xb, unsigned short* __restrict__ Yb,
                            float* __restrict__ sqX, float* __restrict__ sqY,
                            float* __restrict__ sX, float* __restrict__ sY,
                            float* __restrict__ T1) {
  const int wave = threadIdx.x >> 6, lane = threadIdx.x & 63;
  const int row = blockIdx.x * 4 + wave;
  const int m = blockIdx.y;
  const float* __restrict__ src = m ? Y : X;
  unsigned short* __restrict__ dst = m ? Yb : Xb;
  float* __restrict__ dsq = m ? sqY : sqX;

  // zero accumulators: each (block,y) pair covers 4 entries of sX or sY
  if (threadIdx.x < 4) {
    float* z = m ? sY : sX;
    z[blockIdx.x * 4 + threadIdx.x] = 0.f;
  }
  if (blockIdx.x == 0 && m == 0 && threadIdx.x == 0) *T1 = 0.f;

  const float4* s4 = (const float4*)(src + (size_t)row * D);
  ushort4* d4 = (ushort4*)(dst + (size_t)row * D);
  float acc = 0.f;
#pragma unroll
  for (int h = 0; h < 2; ++h) {
    float4 v = s4[lane + h * 64];
    acc += v.x * v.x + v.y * v.y + v.z * v.z + v.w * v.w;
    ushort4 o;
    o.x = f2bf(v.x); o.y = f2bf(v.y); o.z = f2bf(v.z); o.w = f2bf(v.w);
    d4[lane + h * 64] = o;
  }
#pragma unroll
  for (int mm = 32; mm >= 1; mm >>= 1) acc += __shfl_xor(acc, mm, 64);
  if (lane == 0) dsq[row] = acc;
}

// Upper-triangular fused Gram+RBF+reductions, 128x128 tiles, 2x2 waves of
// 64x64. Double-buffered K-loop (R5: one barrier/iter, prefetch k+1 flies
// during compute of k). XCD-AWARE SWIZZLE (R6): with XCD = blockIdx%8
// round-robin, remap t = (b%8)*66 + b/8 so each XCD's 64-66 resident blocks
// work a CONTIGUOUS segment of the row-major triangle -> A-panels reused
// ~30x and B-panels 2-3x inside one XCD's 4MB L2, instead of ~32MB of
// random panels thrashing it (R5 theory: staging was L3/HBM-fed at ~3TB/s).
// NO device fences (R3: per-block agent fence = L2 writeback storm, 5x).
// launch_bounds stays (256,2): (256,4) forced 128-VGPR cap -> spills (R4).
__launch_bounds__(256, 2)
__global__ void hsic_main(const __hip_bfloat16* __restrict__ Xbh,
                          const __hip_bfloat16* __restrict__ Ybh,
                          const float* __restrict__ sqX, const float* __restrict__ sqY,
                          float* __restrict__ sX, float* __restrict__ sY,
                          float* __restrict__ T1) {
  // [buf][tile]: tiles Ax, Bx, Ay, By each BM*BK elements; 64 KB total
  __shared__ __align__(16) __bf16 smem[2][4 * TILE];

  // XCD-contiguous segment swizzle (bijection on [0,528): 528 = 8*66)
  const int b = blockIdx.x;
  int idx = (b & 7) * (NBLK / 8) + (b >> 3);

  // triangular decode: idx -> (bI, bJ) with bJ >= bI (row-major triangle)
  const float nf = (float)NB + 0.5f;
  int bI = (int)(nf - sqrtf(nf * nf - 2.0f * (float)idx));
  if (bI < 0) bI = 0;
  if (bI >= NB) bI = NB - 1;
  while (bI * NB - bI * (bI - 1) / 2 > idx) --bI;
  while ((bI + 1) * NB - (bI + 1) * bI / 2 <= idx) ++bI;
  const int bJ = bI + (idx - (bI * NB - bI * (bI - 1) / 2));
  const bool offdiag = (bI != bJ);

  const int tid = threadIdx.x;
  const int lane = tid & 63, wave = tid >> 6;
  const int wm = wave >> 1, wn = wave & 1;   // 2x2 wave grid, each wave 64x64
  const int quad = lane >> 4, cl = lane & 15;

  const __bf16* Xb = (const __bf16*)Xbh;
  const __bf16* Yb = (const __bf16*)Ybh;
  const __bf16* gAx = Xb + (size_t)bI * BM * D;
  const __bf16* gBx = Xb + (size_t)bJ * BM * D;
  const __bf16* gAy = Yb + (size_t)bI * BM * D;
  const __bf16* gBy = Yb + (size_t)bJ * BM * D;

  floatx4 accX[4][4];
  floatx4 accY[4][4];
#pragma unroll
  for (int i = 0; i < 4; ++i)
#pragma unroll
    for (int j = 0; j < 4; ++j) {
      accX[i][j] = (floatx4){0.f, 0.f, 0.f, 0.f};
      accY[i][j] = (floatx4){0.f, 0.f, 0.f, 0.f};
    }

  // staging: each tile is 512 16B-chunks; 256 threads x 2 chunks.
  // chunk c: row = c>>2, col8 = (c&3)*8; LDS elem dest = c*8 (lane-contiguous)
  auto stage_all = [&](int kt, int buf) {
    const int k0 = kt * BK;
#pragma unroll
    for (int h = 0; h < 2; ++h) {
      const int c = tid + h * 256;
      const int r = c >> 2;
      const int col = (c & 3) * 8;
      const size_t goff = (size_t)r * D + k0 + col;
      const int loff = c * 8;
      stage16(gAx + goff, &smem[buf][0 * TILE + loff]);
      stage16(gBx + goff, &smem[buf][1 * TILE + loff]);
      stage16(gAy + goff, &smem[buf][2 * TILE + loff]);
      stage16(gBy + goff, &smem[buf][3 * TILE + loff]);
    }
  };

  stage_all(0, 0);

  for (int kt = 0; kt < KITERS; ++kt) {
    const int buf = kt & 1;
    // drains stage(kt) [vmcnt(0) emitted before s_barrier]; also separates
    // prior reads of buf^1 (iter kt-1) from the prefetch writes below
    __syncthreads();
    if (kt + 1 < KITERS) stage_all(kt + 1, buf ^ 1);

    const __bf16* Ax = &smem[buf][0 * TILE];
    const __bf16* Bx = &smem[buf][1 * TILE];
    const __bf16* Ay = &smem[buf][2 * TILE];
    const __bf16* By = &smem[buf][3 * TILE];

    bf16x8 bxf[4], byf[4];
#pragma unroll
    for (int ni = 0; ni < 4; ++ni) {
      const int rr = wn * 64 + ni * 16 + cl;
      const int off = rr * BK + quad * 8;
      bxf[ni] = *(const bf16x8*)&Bx[off];
      byf[ni] = *(const bf16x8*)&By[off];
    }
#pragma unroll
    for (int mi = 0; mi < 4; ++mi) {
      const int rr = wm * 64 + mi * 16 + cl;
      const int off = rr * BK + quad * 8;
      bf16x8 axf = *(const bf16x8*)&Ax[off];
      bf16x8 ayf = *(const bf16x8*)&Ay[off];
#pragma unroll
      for (int ni = 0; ni < 4; ++ni) {
        accX[mi][ni] = __builtin_amdgcn_mfma_f32_16x16x32_bf16(axf, bxf[ni], accX[mi][ni], 0, 0, 0);
        accY[mi][ni] = __builtin_amdgcn_mfma_f32_16x16x32_bf16(ayf, byf[ni], accY[mi][ni], 0, 0, 0);
      }
    }
  }

  // ---- epilogue ----
  // C/D layout (m89-verified): col = lane&15, row = (lane>>4)*4 + reg
  const int Ib = bI * BM + wm * 64;
  const int Jb = bJ * BM + wn * 64;
  float t1l = 0.f;
  float rx[4][4], ry[4][4];  // [mi][reg] row-sum partials over this wave's 64 cols
  float cx[4], cy[4];        // [ni] col-sum partials over this lane's 16 rows
#pragma unroll
  for (int mi = 0; mi < 4; ++mi)
#pragma unroll
    for (int r = 0; r < 4; ++r) { rx[mi][r] = 0.f; ry[mi][r] = 0.f; }
#pragma unroll
  for (int ni = 0; ni < 4; ++ni) { cx[ni] = 0.f; cy[ni] = 0.f; }

  bool wave_any = false;  // wave-uniform after __any-gated updates

#pragma unroll
  for (int mi = 0; mi < 4; ++mi) {
    const int ig0 = Ib + mi * 16 + quad * 4;
    float sxi[4], syi[4];
#pragma unroll
    for (int r = 0; r < 4; ++r) { sxi[r] = sqX[ig0 + r]; syi[r] = sqY[ig0 + r]; }
#pragma unroll
    for (int ni = 0; ni < 4; ++ni) {
      const int jg = Jb + ni * 16 + cl;
      const float sxj = sqX[jg];
      const float syj = sqY[jg];
      float d2x[4], d2y[4];
      bool lflag = false;
#pragma unroll
      for (int r = 0; r < 4; ++r) {
        const int ig = ig0 + r;
        d2x[r] = sxi[r] + sxj - 2.f * accX[mi][ni][r];
        d2y[r] = syi[r] + syj - 2.f * accY[mi][ni][r];
        lflag |= (d2x[r] < D2_SKIP) | (d2y[r] < D2_SKIP) | (ig == jg);
      }
      if (__any(lflag)) {   // wave-uniform: skipped entries are all exactly +0.0f
        wave_any = true;
#pragma unroll
        for (int r = 0; r < 4; ++r) {
          const int ig = ig0 + r;
          float kx, ky;
          if (ig == jg) {
            kx = 1.f; ky = 1.f;  // exact diagonal: d2 == 0 mathematically
          } else {
            kx = __expf(-0.5f * d2x[r]);
            ky = __expf(-0.5f * d2y[r]);
          }
          t1l += kx * ky;
          rx[mi][r] += kx;
          ry[mi][r] += ky;
          cx[ni] += kx;
          cy[ni] += ky;
        }
      }
    }
  }

  if (wave_any) {
    // row sums: reduce across the 16 columns (lanes cl=0..15 within each quad)
#pragma unroll
    for (int mi = 0; mi < 4; ++mi)
#pragma unroll
      for (int r = 0; r < 4; ++r) {
        float vx = rx[mi][r], vy = ry[mi][r];
#pragma unroll
        for (int mm = 1; mm < 16; mm <<= 1) {
          vx += __shfl_xor(vx, mm, 16);
          vy += __shfl_xor(vy, mm, 16);
        }
        rx[mi][r] = vx; ry[mi][r] = vy;
      }
    if (cl == 0) {
#pragma unroll
      for (int mi = 0; mi < 4; ++mi)
#pragma unroll
        for (int r = 0; r < 4; ++r) {
          const int row = Ib + mi * 16 + quad * 4 + r;
          atomicAdd(&sX[row], rx[mi][r]);
          atomicAdd(&sY[row], ry[mi][r]);
        }
    }

    // col sums (off-diagonal only): reduce across quads, quad 0 holds totals
    if (offdiag) {
#pragma unroll
      for (int ni = 0; ni < 4; ++ni) {
        float vx = cx[ni], vy = cy[ni];
        vx += __shfl_xor(vx, 16, 64); vy += __shfl_xor(vy, 16, 64);
        vx += __shfl_xor(vx, 32, 64); vy += __shfl_xor(vy, 32, 64);
        if (quad == 0) {
          const int col = Jb + ni * 16 + cl;
          atomicAdd(&sX[col], vx);
          atomicAdd(&sY[col], vy);
        }
      }
    }

    // T1 wave reduction (off-diagonal tiles count twice by symmetry)
    t1l *= offdiag ? 2.f : 1.f;
#pragma unroll
    for (int mm = 1; mm < 64; mm <<= 1) t1l += __shfl_xor(t1l, mm, 64);
  }
  // if !wave_any, t1l == 0 uniformly; no reduction needed
  __shared__ float tred[4];
  if (lane == 0) tred[wave] = t1l;
  __syncthreads();
  if (tid == 0) {
    const float t = tred[0] + tred[1] + tred[2] + tred[3];
    if (t != 0.f) atomicAdd(T1, t);
  }
}

// hsic = (T1 - (2/n) sum sX_i sY_i + (SX*SY)/n^2) / (n-1)^2
__global__ void final_kernel(const float* __restrict__ sX, const float* __restrict__ sY,
                             const float* __restrict__ T1, float* __restrict__ out) {
  const int tid = threadIdx.x;
  float dp = 0.f, sa = 0.f, sb = 0.f;
  for (int i = tid; i < N; i += 256) {
    float a = sX[i], b = sY[i];
    dp += a * b; sa += a; sb += b;
  }
#pragma unroll
  for (int mm = 1; mm < 64; mm <<= 1) {
    dp += __shfl_xor(dp, mm, 64);
    sa += __shfl_xor(sa, mm, 64);
    sb += __shfl_xor(sb, mm, 64);
  }
  __shared__ float r0[4], r1[4], r2[4];
  if ((tid & 63) == 0) { int w = tid >> 6; r0[w] = dp; r1[w] = sa; r2[w] = sb; }
  __syncthreads();
  if (tid == 0) {
    dp = r0[0] + r0[1] + r0[2] + r0[3];
    sa = r1[0] + r1[1] + r1[2] + r1[3];
    sb = r2[0] + r2[1] + r2[2] + r2[3];
    const float n = (float)N;
    const float total = T1[0] - (2.f / n) * dp + (sa * sb) / (n * n);
    out[0] = total / ((n - 1.f) * (n - 1.f));
  }
}

}  // namespace

extern "C" void kernel_launch(void* const* d_in, const int* in_sizes, int n_in,
                              void* d_out, int out_size, void* d_ws, size_t ws_size,
                              hipStream_t stream) {
  const float* X = (const float*)d_in[0];
  const float* Y = (const float*)d_in[1];
  char* ws = (char*)d_ws;
  if (ws_size < WS_NEED) return;

  unsigned short* Xb = (unsigned short*)(ws + OFF_XB);
  unsigned short* Yb = (unsigned short*)(ws + OFF_YB);
  float* sqX = (float*)(ws + OFF_SQX);
  float* sqY = (float*)(ws + OFF_SQY);
  float* sX  = (float*)(ws + OFF_SX);
  float* sY  = (float*)(ws + OFF_SY);
  float* T1  = (float*)(ws + OFF_T1);
  float* out = (float*)d_out;

  prep_kernel<<<dim3(N / 4, 2), 256, 0, stream>>>(X, Y, Xb, Yb, sqX, sqY, sX, sY, T1);
  hsic_main<<<NBLK, 256, 0, stream>>>((const __hip_bfloat16*)Xb, (const __hip_bfloat16*)Yb,
                                      sqX, sqY, sX, sY, T1);
  final_kernel<<<1, 256, 0, stream>>>(sX, sY, T1, out);
}